// Round 1
// 194.404 us; speedup vs baseline: 1.0352x; 1.0352x over previous
//
#include <hip/hip_runtime.h>
#include <hip/hip_bf16.h>
#include <cstdint>

typedef unsigned short u16;
typedef __attribute__((ext_vector_type(8))) short short8;
typedef __attribute__((ext_vector_type(4))) float f32x4;
typedef __attribute__((ext_vector_type(4))) unsigned short us4;

__device__ __forceinline__ u16 f2bf(float f) {
    union { float f; unsigned int i; } v; v.f = f;
    unsigned int x = v.i;
    unsigned int r = x + 0x7fffu + ((x >> 16) & 1u);  // RNE
    return (u16)(r >> 16);
}

enum { EPI_F32 = 0, EPI_BF16 = 1, EPI_EXP_RS = 3, EPI_F32_DIV_CB = 4, EPI_LMSM = 5 };

// C[M,N] = A[M,K] * B[N,K]^T (both K-contiguous), batched via blockIdx.z.
// BK=64, 256 threads (4 waves 2x2). bf16 operands stage via global_load_lds(16B)
// with XOR-8 swizzle applied on the GLOBAL address side (LDS lane mapping fixed:
// base + lane*16): chunk slot c_l of row r holds global chunk c_l^(r&7).
// f32 operands (AF32/BF32) reg-stage: 2x float4 load at the SAME swizzled global
// chunk -> RNE-convert -> one ds_write_b128 into the identical LDS slot, so the
// fragment-read path (XOR-inverting, bank-balanced ds_read_b128) is unchanged.
// A2x: optional second A source; rows >= M/2 come from it (q/k concat case).
template <int BM, int BN, int EPI, bool AF32, bool BF32>
__global__ void __launch_bounds__(256)
gemm_bt(const void* __restrict__ Ax, const void* __restrict__ A2x,
        const void* __restrict__ Bx, void* __restrict__ Cv,
        int M, int N, int K, long sA, long sB, long sC,
        const float* __restrict__ biasCol, float* __restrict__ rowScale, float expScale)
{
    constexpr int BK = 64;
    constexpr int MFRAG = (BM + 31) / 32;   // per-wave 16-row frags (wave covers BM/2)
    constexpr int NFRAG = BN / 32;
    constexpr int AG = (BM + 31) / 32;      // 32-row staging groups
    constexpr int BG = BN / 32;
    __shared__ alignas(16) u16 As[BM * BK];
    __shared__ alignas(16) u16 Bs[BN * BK];

    const int tid = threadIdx.x;
    const int lane = tid & 63;
    const int quad = lane >> 4;
    const int l15 = lane & 15;
    const int w = tid >> 6;
    const int wm = w >> 1, wn = w & 1;
    const int z = blockIdx.z;
    const int m0 = blockIdx.y * BM;
    const int n0 = blockIdx.x * BN;

    const int r8 = tid >> 3;                    // 0..31 staging row within group
    const int cl = tid & 7;                     // LDS chunk slot (16B units)
    const int cg = ((cl ^ (r8 & 7)) * 8);       // swizzled global chunk (elements)

    const u16* ap[AG];
    const float* apf[AG];
    if constexpr (AF32) {
        const float* base = (const float*)Ax;
        long mr = m0;
        if (A2x != nullptr && m0 >= (M >> 1)) { base = (const float*)A2x; mr = m0 - (M >> 1); }
        const float* Afb = base + (long)z * sA + (long)mr * K;
#pragma unroll
        for (int j = 0; j < AG; ++j) apf[j] = Afb + (long)(j * 32 + r8) * K + cg;
    } else {
        const u16* Ab = (const u16*)Ax + (long)z * sA + (long)m0 * K;
#pragma unroll
        for (int j = 0; j < AG; ++j) ap[j] = Ab + (long)(j * 32 + r8) * K + cg;
    }
    const u16* bp[BG];
    const float* bpf[BG];
    if constexpr (BF32) {
        const float* Bfb = (const float*)Bx + (long)z * sB + (long)n0 * K;
#pragma unroll
        for (int j = 0; j < BG; ++j) bpf[j] = Bfb + (long)(j * 32 + r8) * K + cg;
    } else {
        const u16* Bb = (const u16*)Bx + (long)z * sB + (long)n0 * K;
#pragma unroll
        for (int j = 0; j < BG; ++j) bp[j] = Bb + (long)(j * 32 + r8) * K + cg;
    }

    f32x4 acc[MFRAG][NFRAG] = {};

    const int sw = l15 & 7;  // row XOR key for fragment reads

    for (int k0 = 0; k0 < K; k0 += BK) {
        if constexpr (!AF32) {
#pragma unroll
            for (int j = 0; j < AG; ++j) {
                __builtin_amdgcn_global_load_lds(
                    (const __attribute__((address_space(1))) void*)(ap[j]),
                    (__attribute__((address_space(3))) void*)(&As[(j * 32 + r8) * BK + cl * 8]),
                    16, 0, 0);
                ap[j] += BK;
            }
        }
        if constexpr (!BF32) {
#pragma unroll
            for (int j = 0; j < BG; ++j) {
                __builtin_amdgcn_global_load_lds(
                    (const __attribute__((address_space(1))) void*)(bp[j]),
                    (__attribute__((address_space(3))) void*)(&Bs[(j * 32 + r8) * BK + cl * 8]),
                    16, 0, 0);
                bp[j] += BK;
            }
        }
        if constexpr (AF32) {
#pragma unroll
            for (int j = 0; j < AG; ++j) {
                const float4 u0 = *(const float4*)(apf[j]);
                const float4 u1 = *(const float4*)(apf[j] + 4);
                short8 o;
                o[0] = (short)f2bf(u0.x); o[1] = (short)f2bf(u0.y);
                o[2] = (short)f2bf(u0.z); o[3] = (short)f2bf(u0.w);
                o[4] = (short)f2bf(u1.x); o[5] = (short)f2bf(u1.y);
                o[6] = (short)f2bf(u1.z); o[7] = (short)f2bf(u1.w);
                *(short8*)&As[(j * 32 + r8) * BK + cl * 8] = o;
                apf[j] += BK;
            }
        }
        if constexpr (BF32) {
#pragma unroll
            for (int j = 0; j < BG; ++j) {
                const float4 u0 = *(const float4*)(bpf[j]);
                const float4 u1 = *(const float4*)(bpf[j] + 4);
                short8 o;
                o[0] = (short)f2bf(u0.x); o[1] = (short)f2bf(u0.y);
                o[2] = (short)f2bf(u0.z); o[3] = (short)f2bf(u0.w);
                o[4] = (short)f2bf(u1.x); o[5] = (short)f2bf(u1.y);
                o[6] = (short)f2bf(u1.z); o[7] = (short)f2bf(u1.w);
                *(short8*)&Bs[(j * 32 + r8) * BK + cl * 8] = o;
                bpf[j] += BK;
            }
        }
        __syncthreads();
#pragma unroll
        for (int ks = 0; ks < 2; ++ks) {
            short8 af[MFRAG], bfr[NFRAG];
#pragma unroll
            for (int i = 0; i < MFRAG; ++i)
                af[i] = *(const short8*)&As[(wm * (BM / 2) + i * 16 + l15) * BK +
                                            (((ks * 4 + quad) ^ sw) * 8)];
#pragma unroll
            for (int i = 0; i < NFRAG; ++i)
                bfr[i] = *(const short8*)&Bs[(wn * (BN / 2) + i * 16 + l15) * BK +
                                             (((ks * 4 + quad) ^ sw) * 8)];
#pragma unroll
            for (int i = 0; i < MFRAG; ++i)
#pragma unroll
                for (int jn = 0; jn < NFRAG; ++jn)
                    acc[i][jn] = __builtin_amdgcn_mfma_f32_16x16x32_bf16(af[i], bfr[jn], acc[i][jn], 0, 0, 0);
        }
        __syncthreads();
    }

    // C/D layout: col=lane&15, row=quad*4+reg (m89/m91 verified).
    if constexpr (EPI == EPI_LMSM) {
        // BM=32, BN=64, grid.x==1: full softmax row inside the block.
        __shared__ float red[2][BM];
        float ev[4][NFRAG];
#pragma unroll
        for (int r = 0; r < 4; ++r) {
            float s = 0.f;
#pragma unroll
            for (int jn = 0; jn < NFRAG; ++jn) {
                const int col = wn * (BN / 2) + jn * 16 + l15;
                float v = exp2f((acc[0][jn][r] + biasCol[col]) * expScale);
                ev[r][jn] = v; s += v;
            }
            s += __shfl_xor(s, 1); s += __shfl_xor(s, 2);
            s += __shfl_xor(s, 4); s += __shfl_xor(s, 8);
            if (l15 == 0) red[wn][wm * 16 + quad * 4 + r] = s;
        }
        __syncthreads();
#pragma unroll
        for (int r = 0; r < 4; ++r) {
            const int mrow = wm * 16 + quad * 4 + r;
            const float inv = 1.0f / (red[0][mrow] + red[1][mrow]);
            const long m = m0 + mrow;
#pragma unroll
            for (int jn = 0; jn < NFRAG; ++jn) {
                const int col = wn * (BN / 2) + jn * 16 + l15;
                ((u16*)Cv)[m * N + col] = f2bf(ev[r][jn] * inv);
            }
        }
        return;
    } else {
#pragma unroll
        for (int i = 0; i < MFRAG; ++i) {
            const int mb = m0 + wm * (BM / 2) + i * 16 + quad * 4;
#pragma unroll
            for (int r = 0; r < 4; ++r) {
                const int m = mb + r;
                float rin = 0.f;
                if constexpr (EPI == EPI_F32_DIV_CB) rin = 1.0f / rowScale[(long)z * M + m];
                float rowsum = 0.f;
#pragma unroll
                for (int jn = 0; jn < NFRAG; ++jn) {
                    const int col = n0 + wn * (BN / 2) + jn * 16 + l15;
                    float v = acc[i][jn][r];
                    if constexpr (EPI == EPI_EXP_RS) { v = exp2f(v * expScale); rowsum += v; }
                    if constexpr (EPI == EPI_F32_DIV_CB) v = v * rin + biasCol[col];
                    if constexpr (EPI == EPI_F32 || EPI == EPI_F32_DIV_CB)
                        ((float*)Cv)[(long)z * sC + (long)m * N + col] = v;
                    else
                        ((u16*)Cv)[(long)z * sC + (long)m * N + col] = f2bf(v);
                }
                if constexpr (EPI == EPI_EXP_RS) {
                    rowsum += __shfl_xor(rowsum, 1);
                    rowsum += __shfl_xor(rowsum, 2);
                    rowsum += __shfl_xor(rowsum, 4);
                    rowsum += __shfl_xor(rowsum, 8);
                    if (l15 == 0) atomicAdd(&rowScale[(long)z * M + m], rowsum);
                }
            }
        }
    }
}

// All prep in ONE launch, block-range dispatched:
//   blocks [0,1088):    cast Wo (1M elems) then Wl (64K elems) f32->bf16
//   blocks [1088,1344): WvT[e,d] = bf16(Wv[d,e]) via padded LDS tile; zero rsc
//   blocks [1344,1600): bocomb = bo + Wo @ bv (one wave per row)
__global__ void __launch_bounds__(256)
prep_all(const float* __restrict__ Wo, const float* __restrict__ Wl,
         const float* __restrict__ Wv, const float* __restrict__ bv,
         const float* __restrict__ bo,
         u16* __restrict__ Wob, u16* __restrict__ Wlb, u16* __restrict__ WvT,
         float* __restrict__ rsc, float* __restrict__ bocomb)
{
    __shared__ float t[64][65];
    const int b = blockIdx.x;
    const int tid = threadIdx.x;
    if (b < 1088) {
        long i = ((long)b * 256 + tid) * 4;
        const float* s; u16* d;
        if (i < 1048576) { s = Wo; d = Wob; }
        else { i -= 1048576; s = Wl; d = Wlb; }
        const float4 v = *(const float4*)(s + i);
        us4 o;
        o.x = f2bf(v.x); o.y = f2bf(v.y); o.z = f2bf(v.z); o.w = f2bf(v.w);
        *(us4*)(d + i) = o;
    } else if (b < 1344) {
        const int bidx = b - 1088;
        const int bx = bidx & 15, by = bidx >> 4;
#pragma unroll
        for (int p = 0; p < 16; ++p) {
            int idx = p * 256 + tid;
            int r = idx >> 6, c = idx & 63;
            t[r][c] = Wv[(long)(by * 64 + r) * 1024 + bx * 64 + c];
        }
        __syncthreads();
#pragma unroll
        for (int p = 0; p < 16; ++p) {
            int idx = p * 256 + tid;
            int c = idx >> 6, r = idx & 63;
            WvT[(long)(bx * 64 + c) * 1024 + by * 64 + r] = f2bf(t[r][c]);
        }
        if (bx == 0) rsc[by * 256 + tid] = 0.f;
    } else {
        const int row = (b - 1344) * 4 + (tid >> 6);
        const int lane = tid & 63;
        float s = 0.f;
#pragma unroll
        for (int i = 0; i < 16; ++i) s += Wo[(long)row * 1024 + i * 64 + lane] * bv[i * 64 + lane];
        for (int o = 32; o; o >>= 1) s += __shfl_xor(s, o, 64);
        if (lane == 0) bocomb[row] = bo[row] + s;
    }
}

extern "C" void kernel_launch(void* const* d_in, const int* in_sizes, int n_in,
                              void* d_out, int out_size, void* d_ws, size_t ws_size,
                              hipStream_t stream)
{
    const float* query = (const float*)d_in[0];
    const float* key   = (const float*)d_in[1];
    const float* value = (const float*)d_in[2];
    const float* Wv    = (const float*)d_in[3];
    const float* bv    = (const float*)d_in[4];
    const float* Wl    = (const float*)d_in[5];
    const float* bl    = (const float*)d_in[6];
    const float* Wo    = (const float*)d_in[7];
    const float* bo    = (const float*)d_in[8];
    float* out = (float*)d_out;

    // B=2, L=2048, E=1024, M_land=64.
    // out = diag(1/rowsum(P)) P value Wov^T + 1*(Wo bv + bo)^T,
    //   P = exp(ql kl^T / 8),  Wov = Wo @ Wv,  Ut = Wov @ value^T.
    // q,k,value are consumed as f32 directly (cast fused into GEMM staging).
    char* ws = (char*)d_ws;
    u16*   Wlb    = (u16*)  (ws + 25165824);   // [64,1024]
    u16*   Wob    = (u16*)  (ws + 25296896);   // [1024,1024]
    u16*   WvT    = (u16*)  (ws + 27394048);   // [1024(e),1024(d)]
    u16*   Wov    = (u16*)  (ws + 29491200);   // [1024(o),1024(e)]
    u16*   qlkl   = (u16*)  (ws + 31588352);   // [8192,64] (ql then kl)
    u16*   Ut     = (u16*)  (ws + 32636928);   // [2,1024(o),2048(k)]
    u16*   Pm     = (u16*)  (ws + 41025536);   // [2,2048,2048]
    float* rsc    = (float*)(ws + 57802752);   // [2,2048] row sums of P
    float* bocomb = (float*)(ws + 57819136);   // [1024]

    // 1) all prep (weight casts + transpose + bias fold + rsc zero)
    prep_all<<<dim3(1600), 256, 0, stream>>>(Wo, Wl, Wv, bv, bo,
                                             Wob, Wlb, WvT, rsc, bocomb);

    // 2) ql/kl = softmax((qk @ Wl^T + bl)/8), q/k read as f32, fused softmax
    gemm_bt<32, 64, EPI_LMSM, true, false><<<dim3(1, 256, 1), 256, 0, stream>>>(
        query, key, Wlb, qlkl, 8192, 64, 1024, 0, 0, 0, bl, nullptr, 0.18033688011112042f);

    // 3) Wov = Wo @ Wv  -> [1024,1024] bf16
    gemm_bt<64, 64, EPI_BF16, false, false><<<dim3(16, 16, 1), 256, 0, stream>>>(
        Wob, nullptr, WvT, Wov, 1024, 1024, 1024, 0, 0, 0, nullptr, nullptr, 0.f);

    // 4) Ut[z] = Wov @ value[z]^T -> [1024,2048] bf16, value read as f32
    gemm_bt<128, 64, EPI_BF16, false, true><<<dim3(32, 8, 2), 256, 0, stream>>>(
        Wov, nullptr, value, Ut, 1024, 2048, 1024, 0, 2097152, 2097152, nullptr, nullptr, 0.f);

    // 5) P[z] = exp(ql kl^T / 8) bf16, fused per-row sums (atomics into rsc)
    gemm_bt<128, 128, EPI_EXP_RS, false, false><<<dim3(16, 16, 2), 256, 0, stream>>>(
        qlkl, nullptr, qlkl + 262144, Pm, 2048, 2048, 64,
        131072, 131072, 4194304, nullptr, rsc, 0.18033688011112042f);

    // 6) out[z] = diag(1/rsc) P[z] @ Ut[z]^T + bocomb -> f32
    gemm_bt<64, 128, EPI_F32_DIV_CB, false, false><<<dim3(8, 32, 2), 256, 0, stream>>>(
        Pm, nullptr, Ut, out, 2048, 1024, 2048,
        4194304, 2097152, 2097152, bocomb, rsc, 0.f);
}

// Round 2
// 178.014 us; speedup vs baseline: 1.1305x; 1.0921x over previous
//
#include <hip/hip_runtime.h>
#include <hip/hip_bf16.h>
#include <cstdint>

typedef unsigned short u16;
typedef __attribute__((ext_vector_type(8))) short short8;
typedef __attribute__((ext_vector_type(4))) float f32x4;
typedef __attribute__((ext_vector_type(4))) unsigned short us4;

__device__ __forceinline__ u16 f2bf(float f) {
    union { float f; unsigned int i; } v; v.f = f;
    unsigned int x = v.i;
    unsigned int r = x + 0x7fffu + ((x >> 16) & 1u);  // RNE
    return (u16)(r >> 16);
}

enum { EPI_F32 = 0, EPI_BF16 = 1, EPI_EXP_RS = 3, EPI_F32_DIV_CB = 4, EPI_LMSM = 5 };

// C[M,N] = A[M,K] * B[N,K]^T (both K-contiguous). BK=64, 256 threads (4 waves
// 2x2). bf16 operands stage via global_load_lds(16B) with XOR-8 swizzle applied
// on the GLOBAL address side (LDS lane mapping fixed: base + lane*16): chunk
// slot c_l of row r holds global chunk c_l^(r&7). Fragment reads invert the
// XOR -> bank-balanced ds_read_b128. f32 operands (AF32/BF32) reg-stage:
// 2x float4 at the SAME swizzled global chunk -> RNE -> one ds_write_b128 into
// the identical LDS slot, so the fragment-read path is unchanged.
// A2x: optional second A source; rows >= M/2 come from it (q/k concat case).
// Device body: tile origin (m0,n0,z) passed in so grid-level fusion can
// dispatch heterogeneous GEMMs from one launch. LDS via caller smem.
template <int BM, int BN, int EPI, bool AF32, bool BF32>
__device__ __forceinline__ void gemm_body(
    char* __restrict__ smem,
    const void* __restrict__ Ax, const void* __restrict__ A2x,
    const void* __restrict__ Bx, void* __restrict__ Cv,
    int M, int N, int K, long sA, long sB, long sC,
    const float* __restrict__ biasCol, float* __restrict__ rowScale, float expScale,
    int m0, int n0, int z)
{
    constexpr int BK = 64;
    constexpr int MFRAG = (BM + 31) / 32;   // per-wave 16-row frags (wave covers BM/2)
    constexpr int NFRAG = BN / 32;
    constexpr int AG = (BM + 31) / 32;      // 32-row staging groups
    constexpr int BG = BN / 32;
    u16* As = (u16*)smem;
    u16* Bs = (u16*)(smem + (long)BM * BK * 2);

    const int tid = threadIdx.x;
    const int lane = tid & 63;
    const int quad = lane >> 4;
    const int l15 = lane & 15;
    const int w = tid >> 6;
    const int wm = w >> 1, wn = w & 1;

    const int r8 = tid >> 3;                    // 0..31 staging row within group
    const int cl = tid & 7;                     // LDS chunk slot (16B units)
    const int cg = ((cl ^ (r8 & 7)) * 8);       // swizzled global chunk (elements)

    const u16* ap[AG];
    const float* apf[AG];
    if constexpr (AF32) {
        const float* base = (const float*)Ax;
        long mr = m0;
        if (A2x != nullptr && m0 >= (M >> 1)) { base = (const float*)A2x; mr = m0 - (M >> 1); }
        const float* Afb = base + (long)z * sA + (long)mr * K;
#pragma unroll
        for (int j = 0; j < AG; ++j) apf[j] = Afb + (long)(j * 32 + r8) * K + cg;
    } else {
        const u16* Ab = (const u16*)Ax + (long)z * sA + (long)m0 * K;
#pragma unroll
        for (int j = 0; j < AG; ++j) ap[j] = Ab + (long)(j * 32 + r8) * K + cg;
    }
    const u16* bp[BG];
    const float* bpf[BG];
    if constexpr (BF32) {
        const float* Bfb = (const float*)Bx + (long)z * sB + (long)n0 * K;
#pragma unroll
        for (int j = 0; j < BG; ++j) bpf[j] = Bfb + (long)(j * 32 + r8) * K + cg;
    } else {
        const u16* Bb = (const u16*)Bx + (long)z * sB + (long)n0 * K;
#pragma unroll
        for (int j = 0; j < BG; ++j) bp[j] = Bb + (long)(j * 32 + r8) * K + cg;
    }

    f32x4 acc[MFRAG][NFRAG] = {};

    const int sw = l15 & 7;  // row XOR key for fragment reads

    for (int k0 = 0; k0 < K; k0 += BK) {
        if constexpr (!AF32) {
#pragma unroll
            for (int j = 0; j < AG; ++j) {
                __builtin_amdgcn_global_load_lds(
                    (const __attribute__((address_space(1))) void*)(ap[j]),
                    (__attribute__((address_space(3))) void*)(&As[(j * 32 + r8) * BK + cl * 8]),
                    16, 0, 0);
                ap[j] += BK;
            }
        }
        if constexpr (!BF32) {
#pragma unroll
            for (int j = 0; j < BG; ++j) {
                __builtin_amdgcn_global_load_lds(
                    (const __attribute__((address_space(1))) void*)(bp[j]),
                    (__attribute__((address_space(3))) void*)(&Bs[(j * 32 + r8) * BK + cl * 8]),
                    16, 0, 0);
                bp[j] += BK;
            }
        }
        if constexpr (AF32) {
#pragma unroll
            for (int j = 0; j < AG; ++j) {
                const float4 u0 = *(const float4*)(apf[j]);
                const float4 u1 = *(const float4*)(apf[j] + 4);
                short8 o;
                o[0] = (short)f2bf(u0.x); o[1] = (short)f2bf(u0.y);
                o[2] = (short)f2bf(u0.z); o[3] = (short)f2bf(u0.w);
                o[4] = (short)f2bf(u1.x); o[5] = (short)f2bf(u1.y);
                o[6] = (short)f2bf(u1.z); o[7] = (short)f2bf(u1.w);
                *(short8*)&As[(j * 32 + r8) * BK + cl * 8] = o;
                apf[j] += BK;
            }
        }
        if constexpr (BF32) {
#pragma unroll
            for (int j = 0; j < BG; ++j) {
                const float4 u0 = *(const float4*)(bpf[j]);
                const float4 u1 = *(const float4*)(bpf[j] + 4);
                short8 o;
                o[0] = (short)f2bf(u0.x); o[1] = (short)f2bf(u0.y);
                o[2] = (short)f2bf(u0.z); o[3] = (short)f2bf(u0.w);
                o[4] = (short)f2bf(u1.x); o[5] = (short)f2bf(u1.y);
                o[6] = (short)f2bf(u1.z); o[7] = (short)f2bf(u1.w);
                *(short8*)&Bs[(j * 32 + r8) * BK + cl * 8] = o;
                bpf[j] += BK;
            }
        }
        __syncthreads();
#pragma unroll
        for (int ks = 0; ks < 2; ++ks) {
            short8 af[MFRAG], bfr[NFRAG];
#pragma unroll
            for (int i = 0; i < MFRAG; ++i)
                af[i] = *(const short8*)&As[(wm * (BM / 2) + i * 16 + l15) * BK +
                                            (((ks * 4 + quad) ^ sw) * 8)];
#pragma unroll
            for (int i = 0; i < NFRAG; ++i)
                bfr[i] = *(const short8*)&Bs[(wn * (BN / 2) + i * 16 + l15) * BK +
                                             (((ks * 4 + quad) ^ sw) * 8)];
#pragma unroll
            for (int i = 0; i < MFRAG; ++i)
#pragma unroll
                for (int jn = 0; jn < NFRAG; ++jn)
                    acc[i][jn] = __builtin_amdgcn_mfma_f32_16x16x32_bf16(af[i], bfr[jn], acc[i][jn], 0, 0, 0);
        }
        __syncthreads();
    }

    // C/D layout: col=lane&15, row=quad*4+reg (m89/m91 verified).
    if constexpr (EPI == EPI_LMSM) {
        // BM=32, BN=64, single n-block: full softmax row inside the block.
        float* red = (float*)(smem + (long)(BM + BN) * BK * 2);  // [2][BM]
        float ev[4][NFRAG];
#pragma unroll
        for (int r = 0; r < 4; ++r) {
            float s = 0.f;
#pragma unroll
            for (int jn = 0; jn < NFRAG; ++jn) {
                const int col = wn * (BN / 2) + jn * 16 + l15;
                float v = exp2f((acc[0][jn][r] + biasCol[col]) * expScale);
                ev[r][jn] = v; s += v;
            }
            s += __shfl_xor(s, 1); s += __shfl_xor(s, 2);
            s += __shfl_xor(s, 4); s += __shfl_xor(s, 8);
            if (l15 == 0) red[wn * BM + wm * 16 + quad * 4 + r] = s;
        }
        __syncthreads();
#pragma unroll
        for (int r = 0; r < 4; ++r) {
            const int mrow = wm * 16 + quad * 4 + r;
            const float inv = 1.0f / (red[mrow] + red[BM + mrow]);
            const long m = m0 + mrow;
#pragma unroll
            for (int jn = 0; jn < NFRAG; ++jn) {
                const int col = wn * (BN / 2) + jn * 16 + l15;
                ((u16*)Cv)[m * N + col] = f2bf(ev[r][jn] * inv);
            }
        }
        return;
    } else {
#pragma unroll
        for (int i = 0; i < MFRAG; ++i) {
            const int mb = m0 + wm * (BM / 2) + i * 16 + quad * 4;
#pragma unroll
            for (int r = 0; r < 4; ++r) {
                const int m = mb + r;
                float rin = 0.f;
                if constexpr (EPI == EPI_F32_DIV_CB) rin = 1.0f / rowScale[(long)z * M + m];
                float rowsum = 0.f;
#pragma unroll
                for (int jn = 0; jn < NFRAG; ++jn) {
                    const int col = n0 + wn * (BN / 2) + jn * 16 + l15;
                    float v = acc[i][jn][r];
                    if constexpr (EPI == EPI_EXP_RS) { v = exp2f(v * expScale); rowsum += v; }
                    if constexpr (EPI == EPI_F32_DIV_CB) v = v * rin + biasCol[col];
                    if constexpr (EPI == EPI_F32 || EPI == EPI_F32_DIV_CB)
                        ((float*)Cv)[(long)z * sC + (long)m * N + col] = v;
                    else
                        ((u16*)Cv)[(long)z * sC + (long)m * N + col] = f2bf(v);
                }
                if constexpr (EPI == EPI_EXP_RS) {
                    rowsum += __shfl_xor(rowsum, 1);
                    rowsum += __shfl_xor(rowsum, 2);
                    rowsum += __shfl_xor(rowsum, 4);
                    rowsum += __shfl_xor(rowsum, 8);
                    if (l15 == 0) atomicAdd(&rowScale[(long)z * M + m], rowsum);
                }
            }
        }
    }
}

// Thin grid wrapper for standalone GEMM launches (gemm6).
template <int BM, int BN, int EPI, bool AF32, bool BF32>
__global__ void __launch_bounds__(256)
gemm_bt(const void* __restrict__ Ax, const void* __restrict__ A2x,
        const void* __restrict__ Bx, void* __restrict__ Cv,
        int M, int N, int K, long sA, long sB, long sC,
        const float* __restrict__ biasCol, float* __restrict__ rowScale, float expScale)
{
    extern __shared__ char smem[];
    gemm_body<BM, BN, EPI, AF32, BF32>(smem, Ax, A2x, Bx, Cv, M, N, K, sA, sB, sC,
                                       biasCol, rowScale, expScale,
                                       blockIdx.y * BM, blockIdx.x * BN, blockIdx.z);
}

// Fused launch A: blocks [0,256) = ql/kl landmark softmax (LMSM, q/k read f32);
//                 blocks [256,512) = Wov = Wo(f32) @ WvT  (independent GEMMs,
// merged at grid level: 2 blocks/CU instead of two serialized 1-block/CU runs).
__global__ void __launch_bounds__(256)
fused23(const float* __restrict__ query, const float* __restrict__ key,
        const u16* __restrict__ Wlb, u16* __restrict__ qlkl,
        const float* __restrict__ bl,
        const float* __restrict__ Wo, const u16* __restrict__ WvT, u16* __restrict__ Wov)
{
    extern __shared__ char smem[];
    const int b = blockIdx.x;
    if (b < 256) {
        gemm_body<32, 64, EPI_LMSM, true, false>(smem, query, key, Wlb, qlkl,
            8192, 64, 1024, 0, 0, 0, bl, nullptr, 0.18033688011112042f,
            b * 32, 0, 0);
    } else {
        const int t = b - 256;
        gemm_body<64, 64, EPI_BF16, true, false>(smem, Wo, nullptr, WvT, Wov,
            1024, 1024, 1024, 0, 0, 0, nullptr, nullptr, 0.f,
            (t >> 4) * 64, (t & 15) * 64, 0);
    }
}

// Fused launch B: blocks [0,512)    = Ut[z] = Wov @ value[z]^T (value read f32);
//                 blocks [512,1024) = P[z] = exp(ql kl^T / 8) + row-sum atomics.
__global__ void __launch_bounds__(256)
fused45(const u16* __restrict__ Wov, const float* __restrict__ value, u16* __restrict__ Ut,
        const u16* __restrict__ qlkl, u16* __restrict__ Pm, float* __restrict__ rsc)
{
    extern __shared__ char smem[];
    const int b = blockIdx.x;
    if (b < 512) {
        const int x = b & 31, y = (b >> 5) & 7, z = b >> 8;
        gemm_body<128, 64, EPI_BF16, false, true>(smem, Wov, nullptr, value, Ut,
            1024, 2048, 1024, 0, 2097152, 2097152, nullptr, nullptr, 0.f,
            y * 128, x * 64, z);
    } else {
        const int t = b - 512;
        const int x = t & 15, y = (t >> 4) & 15, z = t >> 8;
        gemm_body<128, 128, EPI_EXP_RS, false, false>(smem, qlkl, nullptr, qlkl + 262144, Pm,
            2048, 2048, 64, 131072, 131072, 4194304, nullptr, rsc, 0.18033688011112042f,
            y * 128, x * 128, z);
    }
}

// Prep in ONE launch, block-range dispatched:
//   blocks [0,64):    cast Wl (64K elems) f32->bf16
//   blocks [64,320):  WvT[e,d] = bf16(Wv[d,e]) via padded LDS tile; zero rsc
//   blocks [320,576): bocomb = bo + Wo @ bv (one wave per row)
__global__ void __launch_bounds__(256)
prep_all(const float* __restrict__ Wl, const float* __restrict__ Wv,
         const float* __restrict__ Wo, const float* __restrict__ bv,
         const float* __restrict__ bo,
         u16* __restrict__ Wlb, u16* __restrict__ WvT,
         float* __restrict__ rsc, float* __restrict__ bocomb)
{
    __shared__ float t[64][65];
    const int b = blockIdx.x;
    const int tid = threadIdx.x;
    if (b < 64) {
        long i = ((long)b * 256 + tid) * 4;
        const float4 v = *(const float4*)(Wl + i);
        us4 o;
        o.x = f2bf(v.x); o.y = f2bf(v.y); o.z = f2bf(v.z); o.w = f2bf(v.w);
        *(us4*)(Wlb + i) = o;
    } else if (b < 320) {
        const int bidx = b - 64;
        const int bx = bidx & 15, by = bidx >> 4;
#pragma unroll
        for (int p = 0; p < 16; ++p) {
            int idx = p * 256 + tid;
            int r = idx >> 6, c = idx & 63;
            t[r][c] = Wv[(long)(by * 64 + r) * 1024 + bx * 64 + c];
        }
        __syncthreads();
#pragma unroll
        for (int p = 0; p < 16; ++p) {
            int idx = p * 256 + tid;
            int c = idx >> 6, r = idx & 63;
            WvT[(long)(bx * 64 + c) * 1024 + by * 64 + r] = f2bf(t[r][c]);
        }
        if (bx == 0) rsc[by * 256 + tid] = 0.f;
    } else {
        const int row = (b - 320) * 4 + (tid >> 6);
        const int lane = tid & 63;
        float s = 0.f;
#pragma unroll
        for (int i = 0; i < 16; ++i) s += Wo[(long)row * 1024 + i * 64 + lane] * bv[i * 64 + lane];
        for (int o = 32; o; o >>= 1) s += __shfl_xor(s, o, 64);
        if (lane == 0) bocomb[row] = bo[row] + s;
    }
}

extern "C" void kernel_launch(void* const* d_in, const int* in_sizes, int n_in,
                              void* d_out, int out_size, void* d_ws, size_t ws_size,
                              hipStream_t stream)
{
    const float* query = (const float*)d_in[0];
    const float* key   = (const float*)d_in[1];
    const float* value = (const float*)d_in[2];
    const float* Wv    = (const float*)d_in[3];
    const float* bv    = (const float*)d_in[4];
    const float* Wl    = (const float*)d_in[5];
    const float* bl    = (const float*)d_in[6];
    const float* Wo    = (const float*)d_in[7];
    const float* bo    = (const float*)d_in[8];
    float* out = (float*)d_out;

    // B=2, L=2048, E=1024, M_land=64.
    // out = diag(1/rowsum(P)) P value Wov^T + 1*(Wo bv + bo)^T,
    //   P = exp(ql kl^T / 8),  Wov = Wo @ Wv,  Ut = Wov @ value^T.
    // q,k,value,Wo consumed as f32 directly (cast fused into GEMM staging).
    // DAG: prep -> {lmsm, wov}(fused23) -> {ut, p}(fused45) -> out(gemm6).
    char* ws = (char*)d_ws;
    u16*   Wlb    = (u16*)  (ws + 25165824);   // [64,1024]
    u16*   WvT    = (u16*)  (ws + 27394048);   // [1024(e),1024(d)]
    u16*   Wov    = (u16*)  (ws + 29491200);   // [1024(o),1024(e)]
    u16*   qlkl   = (u16*)  (ws + 31588352);   // [8192,64] (ql then kl)
    u16*   Ut     = (u16*)  (ws + 32636928);   // [2,1024(o),2048(k)]
    u16*   Pm     = (u16*)  (ws + 41025536);   // [2,2048,2048]
    float* rsc    = (float*)(ws + 57802752);   // [2,2048] row sums of P
    float* bocomb = (float*)(ws + 57819136);   // [1024]

    // 1) prep (Wl cast + Wv transpose-cast + bias fold + rsc zero)
    prep_all<<<dim3(576), 256, 0, stream>>>(Wl, Wv, Wo, bv, bo,
                                            Wlb, WvT, rsc, bocomb);

    // 2+3) ql/kl landmark softmax  ||  Wov = Wo @ Wv   (one launch, 512 blocks)
    fused23<<<dim3(512), 256, 16384, stream>>>(query, key, Wlb, qlkl, bl,
                                               Wo, WvT, Wov);

    // 4+5) Ut[z] = Wov @ value[z]^T  ||  P[z] = exp(ql kl^T/8) + rowsums
    fused45<<<dim3(1024), 256, 32768, stream>>>(Wov, value, Ut, qlkl, Pm, rsc);

    // 6) out[z] = diag(1/rsc) P[z] @ Ut[z]^T + bocomb -> f32
    gemm_bt<64, 128, EPI_F32_DIV_CB, false, false>
        <<<dim3(8, 32, 2), 256, 24576, stream>>>(
        Pm, nullptr, Ut, out, 2048, 1024, 2048,
        4194304, 2097152, 2097152, bocomb, rsc, 0.f);
}

// Round 3
// 170.978 us; speedup vs baseline: 1.1771x; 1.0412x over previous
//
#include <hip/hip_runtime.h>
#include <hip/hip_bf16.h>
#include <cstdint>

typedef unsigned short u16;
typedef __attribute__((ext_vector_type(8))) short short8;
typedef __attribute__((ext_vector_type(4))) float f32x4;
typedef __attribute__((ext_vector_type(4))) unsigned short us4;

__device__ __forceinline__ u16 f2bf(float f) {
    union { float f; unsigned int i; } v; v.f = f;
    unsigned int x = v.i;
    unsigned int r = x + 0x7fffu + ((x >> 16) & 1u);  // RNE
    return (u16)(r >> 16);
}

enum { EPI_F32 = 0, EPI_BF16 = 1, EPI_EXP_RS = 3, EPI_F32_DIV_CB = 4, EPI_LMSM = 5 };

// C[M,N] = A[M,K] * B[N,K]^T (both K-contiguous). BK=64, 256 threads (4 waves
// 2x2). bf16 operands stage via global_load_lds(16B) with XOR-8 swizzle applied
// on the GLOBAL address side (LDS lane mapping fixed: base + lane*16): chunk
// slot c_l of row r holds global chunk c_l^(r&7). Fragment reads invert the
// XOR -> bank-balanced ds_read_b128. f32 operands (AF32/BF32) reg-stage:
// 2x float4 at the SAME swizzled global chunk -> RNE -> one ds_write_b128 into
// the identical LDS slot, so the fragment-read path is unchanged.
// A2x: optional second A source; rows >= M/2 come from it (q/k concat case).
template <int BM, int BN, int EPI, bool AF32, bool BF32>
__device__ __forceinline__ void gemm_body(
    char* __restrict__ smem,
    const void* __restrict__ Ax, const void* __restrict__ A2x,
    const void* __restrict__ Bx, void* __restrict__ Cv,
    int M, int N, int K, long sA, long sB, long sC,
    const float* __restrict__ biasCol, float* __restrict__ rowScale, float expScale,
    int m0, int n0, int z)
{
    constexpr int BK = 64;
    constexpr int MFRAG = (BM + 31) / 32;   // per-wave 16-row frags (wave covers BM/2)
    constexpr int NFRAG = BN / 32;
    constexpr int AG = (BM + 31) / 32;      // 32-row staging groups
    constexpr int BG = BN / 32;
    u16* As = (u16*)smem;
    u16* Bs = (u16*)(smem + (long)BM * BK * 2);

    const int tid = threadIdx.x;
    const int lane = tid & 63;
    const int quad = lane >> 4;
    const int l15 = lane & 15;
    const int w = tid >> 6;
    const int wm = w >> 1, wn = w & 1;

    const int r8 = tid >> 3;                    // 0..31 staging row within group
    const int cl = tid & 7;                     // LDS chunk slot (16B units)
    const int cg = ((cl ^ (r8 & 7)) * 8);       // swizzled global chunk (elements)

    const u16* ap[AG];
    const float* apf[AG];
    if constexpr (AF32) {
        const float* base = (const float*)Ax;
        long mr = m0;
        if (A2x != nullptr && m0 >= (M >> 1)) { base = (const float*)A2x; mr = m0 - (M >> 1); }
        const float* Afb = base + (long)z * sA + (long)mr * K;
#pragma unroll
        for (int j = 0; j < AG; ++j) apf[j] = Afb + (long)(j * 32 + r8) * K + cg;
    } else {
        const u16* Ab = (const u16*)Ax + (long)z * sA + (long)m0 * K;
#pragma unroll
        for (int j = 0; j < AG; ++j) ap[j] = Ab + (long)(j * 32 + r8) * K + cg;
    }
    const u16* bp[BG];
    const float* bpf[BG];
    if constexpr (BF32) {
        const float* Bfb = (const float*)Bx + (long)z * sB + (long)n0 * K;
#pragma unroll
        for (int j = 0; j < BG; ++j) bpf[j] = Bfb + (long)(j * 32 + r8) * K + cg;
    } else {
        const u16* Bb = (const u16*)Bx + (long)z * sB + (long)n0 * K;
#pragma unroll
        for (int j = 0; j < BG; ++j) bp[j] = Bb + (long)(j * 32 + r8) * K + cg;
    }

    f32x4 acc[MFRAG][NFRAG] = {};

    const int sw = l15 & 7;  // row XOR key for fragment reads

    for (int k0 = 0; k0 < K; k0 += BK) {
        if constexpr (!AF32) {
#pragma unroll
            for (int j = 0; j < AG; ++j) {
                __builtin_amdgcn_global_load_lds(
                    (const __attribute__((address_space(1))) void*)(ap[j]),
                    (__attribute__((address_space(3))) void*)(&As[(j * 32 + r8) * BK + cl * 8]),
                    16, 0, 0);
                ap[j] += BK;
            }
        }
        if constexpr (!BF32) {
#pragma unroll
            for (int j = 0; j < BG; ++j) {
                __builtin_amdgcn_global_load_lds(
                    (const __attribute__((address_space(1))) void*)(bp[j]),
                    (__attribute__((address_space(3))) void*)(&Bs[(j * 32 + r8) * BK + cl * 8]),
                    16, 0, 0);
                bp[j] += BK;
            }
        }
        if constexpr (AF32) {
#pragma unroll
            for (int j = 0; j < AG; ++j) {
                const float4 u0 = *(const float4*)(apf[j]);
                const float4 u1 = *(const float4*)(apf[j] + 4);
                short8 o;
                o[0] = (short)f2bf(u0.x); o[1] = (short)f2bf(u0.y);
                o[2] = (short)f2bf(u0.z); o[3] = (short)f2bf(u0.w);
                o[4] = (short)f2bf(u1.x); o[5] = (short)f2bf(u1.y);
                o[6] = (short)f2bf(u1.z); o[7] = (short)f2bf(u1.w);
                *(short8*)&As[(j * 32 + r8) * BK + cl * 8] = o;
                apf[j] += BK;
            }
        }
        if constexpr (BF32) {
#pragma unroll
            for (int j = 0; j < BG; ++j) {
                const float4 u0 = *(const float4*)(bpf[j]);
                const float4 u1 = *(const float4*)(bpf[j] + 4);
                short8 o;
                o[0] = (short)f2bf(u0.x); o[1] = (short)f2bf(u0.y);
                o[2] = (short)f2bf(u0.z); o[3] = (short)f2bf(u0.w);
                o[4] = (short)f2bf(u1.x); o[5] = (short)f2bf(u1.y);
                o[6] = (short)f2bf(u1.z); o[7] = (short)f2bf(u1.w);
                *(short8*)&Bs[(j * 32 + r8) * BK + cl * 8] = o;
                bpf[j] += BK;
            }
        }
        __syncthreads();
#pragma unroll
        for (int ks = 0; ks < 2; ++ks) {
            short8 af[MFRAG], bfr[NFRAG];
#pragma unroll
            for (int i = 0; i < MFRAG; ++i)
                af[i] = *(const short8*)&As[(wm * (BM / 2) + i * 16 + l15) * BK +
                                            (((ks * 4 + quad) ^ sw) * 8)];
#pragma unroll
            for (int i = 0; i < NFRAG; ++i)
                bfr[i] = *(const short8*)&Bs[(wn * (BN / 2) + i * 16 + l15) * BK +
                                             (((ks * 4 + quad) ^ sw) * 8)];
#pragma unroll
            for (int i = 0; i < MFRAG; ++i)
#pragma unroll
                for (int jn = 0; jn < NFRAG; ++jn)
                    acc[i][jn] = __builtin_amdgcn_mfma_f32_16x16x32_bf16(af[i], bfr[jn], acc[i][jn], 0, 0, 0);
        }
        __syncthreads();
    }

    // C/D layout: col=lane&15, row=quad*4+reg (m89/m91 verified).
    if constexpr (EPI == EPI_LMSM) {
        // BM=32, BN=64, single n-block: full softmax row inside the block.
        float* red = (float*)(smem + (long)(BM + BN) * BK * 2);  // [2][BM]
        float ev[4][NFRAG];
#pragma unroll
        for (int r = 0; r < 4; ++r) {
            float s = 0.f;
#pragma unroll
            for (int jn = 0; jn < NFRAG; ++jn) {
                const int col = wn * (BN / 2) + jn * 16 + l15;
                float v = exp2f((acc[0][jn][r] + biasCol[col]) * expScale);
                ev[r][jn] = v; s += v;
            }
            s += __shfl_xor(s, 1); s += __shfl_xor(s, 2);
            s += __shfl_xor(s, 4); s += __shfl_xor(s, 8);
            if (l15 == 0) red[wn * BM + wm * 16 + quad * 4 + r] = s;
        }
        __syncthreads();
#pragma unroll
        for (int r = 0; r < 4; ++r) {
            const int mrow = wm * 16 + quad * 4 + r;
            const float inv = 1.0f / (red[mrow] + red[BM + mrow]);
            const long m = m0 + mrow;
#pragma unroll
            for (int jn = 0; jn < NFRAG; ++jn) {
                const int col = wn * (BN / 2) + jn * 16 + l15;
                ((u16*)Cv)[m * N + col] = f2bf(ev[r][jn] * inv);
            }
        }
        return;
    } else {
#pragma unroll
        for (int i = 0; i < MFRAG; ++i) {
            const int mb = m0 + wm * (BM / 2) + i * 16 + quad * 4;
#pragma unroll
            for (int r = 0; r < 4; ++r) {
                const int m = mb + r;
                float rin = 0.f;
                if constexpr (EPI == EPI_F32_DIV_CB) rin = 1.0f / rowScale[(long)z * M + m];
                float rowsum = 0.f;
#pragma unroll
                for (int jn = 0; jn < NFRAG; ++jn) {
                    const int col = n0 + wn * (BN / 2) + jn * 16 + l15;
                    float v = acc[i][jn][r];
                    if constexpr (EPI == EPI_EXP_RS) { v = exp2f(v * expScale); rowsum += v; }
                    if constexpr (EPI == EPI_F32_DIV_CB) v = v * rin + biasCol[col];
                    if constexpr (EPI == EPI_F32 || EPI == EPI_F32_DIV_CB)
                        ((float*)Cv)[(long)z * sC + (long)m * N + col] = v;
                    else
                        ((u16*)Cv)[(long)z * sC + (long)m * N + col] = f2bf(v);
                }
                if constexpr (EPI == EPI_EXP_RS) {
                    rowsum += __shfl_xor(rowsum, 1);
                    rowsum += __shfl_xor(rowsum, 2);
                    rowsum += __shfl_xor(rowsum, 4);
                    rowsum += __shfl_xor(rowsum, 8);
                    if (l15 == 0) atomicAdd(&rowScale[(long)z * M + m], rowsum);
                }
            }
        }
    }
}

// Fused launch A: blocks [0,256) = ql/kl landmark softmax (LMSM, q/k read f32);
//                 blocks [256,512) = Wov = Wo(f32) @ WvT  (independent GEMMs,
// merged at grid level: 2 blocks/CU instead of two serialized 1-block/CU runs).
__global__ void __launch_bounds__(256)
fused23(const float* __restrict__ query, const float* __restrict__ key,
        const u16* __restrict__ Wlb, u16* __restrict__ qlkl,
        const float* __restrict__ bl,
        const float* __restrict__ Wo, const u16* __restrict__ WvT, u16* __restrict__ Wov)
{
    extern __shared__ char smem[];
    const int b = blockIdx.x;
    if (b < 256) {
        gemm_body<32, 64, EPI_LMSM, true, false>(smem, query, key, Wlb, qlkl,
            8192, 64, 1024, 0, 0, 0, bl, nullptr, 0.18033688011112042f,
            b * 32, 0, 0);
    } else {
        const int t = b - 256;
        gemm_body<64, 64, EPI_BF16, true, false>(smem, Wo, nullptr, WvT, Wov,
            1024, 1024, 1024, 0, 0, 0, nullptr, nullptr, 0.f,
            (t >> 4) * 64, (t & 15) * 64, 0);
    }
}

// Fused launch B: blocks [0,512)    = Ut[z] = Wov @ value[z]^T (value read f32);
//                 blocks [512,1024) = P[z] = exp(ql kl^T / 8) + row-sum atomics.
__global__ void __launch_bounds__(256)
fused45(const u16* __restrict__ Wov, const float* __restrict__ value, u16* __restrict__ Ut,
        const u16* __restrict__ qlkl, u16* __restrict__ Pm, float* __restrict__ rsc)
{
    extern __shared__ char smem[];
    const int b = blockIdx.x;
    if (b < 512) {
        const int x = b & 31, y = (b >> 5) & 7, z = b >> 8;
        gemm_body<128, 64, EPI_BF16, false, true>(smem, Wov, nullptr, value, Ut,
            1024, 2048, 1024, 0, 2097152, 2097152, nullptr, nullptr, 0.f,
            y * 128, x * 64, z);
    } else {
        const int t = b - 512;
        const int x = t & 15, y = (t >> 4) & 15, z = t >> 8;
        gemm_body<128, 128, EPI_EXP_RS, false, false>(smem, qlkl, nullptr, qlkl + 262144, Pm,
            2048, 2048, 64, 131072, 131072, 4194304, nullptr, rsc, 0.18033688011112042f,
            y * 128, x * 128, z);
    }
}

// gemm6 split-K: out[z] = diag(1/rsc) P[z] @ Ut[z]^T + bocomb, f32 out.
// 512 threads = 2 K-half groups x 4 waves (2x2). Each group runs the standard
// BM=64/BN=128 BK=64 flow over its K=1024 half with a private 24KB LDS tile
// pair (48KB total -> 2 blocks/CU, 16 waves/CU = 4 independent load streams).
// Final reduce: group1 dumps acc through LDS (conflict-free (chunk*256+tid)*16B
// layout, arena reused after last barrier), group0 adds + rin/bias + stores.
__global__ void __launch_bounds__(512)
gemm6_sk(const u16* __restrict__ Pm, const u16* __restrict__ Ut, float* __restrict__ out,
         const float* __restrict__ bocomb, const float* __restrict__ rsc)
{
    extern __shared__ char smem[];  // [2][24KB]: As 8KB + Bs 16KB per K-half
    const int tid = threadIdx.x;
    const int kh = tid >> 8;            // K-half group id
    const int gtid = tid & 255;
    const int lane = tid & 63;
    const int quad = lane >> 4;
    const int l15 = lane & 15;
    const int w4 = (tid >> 6) & 3;
    const int wm = w4 >> 1, wn = w4 & 1;
    const int z = blockIdx.z;
    const int m0 = blockIdx.y * 64;
    const int n0 = blockIdx.x * 128;

    u16* As = (u16*)(smem + kh * 24576);
    u16* Bs = As + 64 * 64;

    const int r8 = gtid >> 3;
    const int cl = gtid & 7;
    const int cg = ((cl ^ (r8 & 7)) * 8);

    const u16* Ab = Pm + (long)z * 4194304 + (long)m0 * 2048 + kh * 1024;
    const u16* Bb = Ut + (long)z * 2097152 + (long)n0 * 2048 + kh * 1024;
    const u16* ap[2];
    const u16* bp[4];
#pragma unroll
    for (int j = 0; j < 2; ++j) ap[j] = Ab + (long)(j * 32 + r8) * 2048 + cg;
#pragma unroll
    for (int j = 0; j < 4; ++j) bp[j] = Bb + (long)(j * 32 + r8) * 2048 + cg;

    f32x4 acc[2][4] = {};
    const int sw = l15 & 7;

    for (int k0 = 0; k0 < 1024; k0 += 64) {
#pragma unroll
        for (int j = 0; j < 2; ++j) {
            __builtin_amdgcn_global_load_lds(
                (const __attribute__((address_space(1))) void*)(ap[j]),
                (__attribute__((address_space(3))) void*)(&As[(j * 32 + r8) * 64 + cl * 8]),
                16, 0, 0);
            ap[j] += 64;
        }
#pragma unroll
        for (int j = 0; j < 4; ++j) {
            __builtin_amdgcn_global_load_lds(
                (const __attribute__((address_space(1))) void*)(bp[j]),
                (__attribute__((address_space(3))) void*)(&Bs[(j * 32 + r8) * 64 + cl * 8]),
                16, 0, 0);
            bp[j] += 64;
        }
        __syncthreads();
#pragma unroll
        for (int ks = 0; ks < 2; ++ks) {
            short8 af[2], bfr[4];
#pragma unroll
            for (int i = 0; i < 2; ++i)
                af[i] = *(const short8*)&As[(wm * 32 + i * 16 + l15) * 64 +
                                            (((ks * 4 + quad) ^ sw) * 8)];
#pragma unroll
            for (int i = 0; i < 4; ++i)
                bfr[i] = *(const short8*)&Bs[(wn * 64 + i * 16 + l15) * 64 +
                                             (((ks * 4 + quad) ^ sw) * 8)];
#pragma unroll
            for (int i = 0; i < 2; ++i)
#pragma unroll
                for (int jn = 0; jn < 4; ++jn)
                    acc[i][jn] = __builtin_amdgcn_mfma_f32_16x16x32_bf16(af[i], bfr[jn], acc[i][jn], 0, 0, 0);
        }
        __syncthreads();
    }

    // Cross-group reduce through the (now dead) tile arena.
    if (kh == 1) {
#pragma unroll
        for (int i = 0; i < 2; ++i)
#pragma unroll
            for (int jn = 0; jn < 4; ++jn)
                *(f32x4*)(smem + (((i * 4 + jn) * 256 + gtid) << 4)) = acc[i][jn];
    }
    __syncthreads();
    if (kh == 0) {
#pragma unroll
        for (int i = 0; i < 2; ++i)
#pragma unroll
            for (int jn = 0; jn < 4; ++jn)
                acc[i][jn] += *(const f32x4*)(smem + (((i * 4 + jn) * 256 + gtid) << 4));
#pragma unroll
        for (int i = 0; i < 2; ++i) {
            const int mb = m0 + wm * 32 + i * 16 + quad * 4;
#pragma unroll
            for (int r = 0; r < 4; ++r) {
                const int m = mb + r;
                const float rin = 1.0f / rsc[z * 2048 + m];
#pragma unroll
                for (int jn = 0; jn < 4; ++jn) {
                    const int col = n0 + wn * 64 + jn * 16 + l15;
                    out[(long)z * 2097152 + (long)m * 1024 + col] =
                        acc[i][jn][r] * rin + bocomb[col];
                }
            }
        }
    }
}

// Prep in ONE launch, block-range dispatched:
//   blocks [0,64):    cast Wl (64K elems) f32->bf16
//   blocks [64,320):  WvT[e,d] = bf16(Wv[d,e]) via padded LDS tile; zero rsc
//   blocks [320,576): bocomb = bo + Wo @ bv (one wave per row)
__global__ void __launch_bounds__(256)
prep_all(const float* __restrict__ Wl, const float* __restrict__ Wv,
         const float* __restrict__ Wo, const float* __restrict__ bv,
         const float* __restrict__ bo,
         u16* __restrict__ Wlb, u16* __restrict__ WvT,
         float* __restrict__ rsc, float* __restrict__ bocomb)
{
    __shared__ float t[64][65];
    const int b = blockIdx.x;
    const int tid = threadIdx.x;
    if (b < 64) {
        long i = ((long)b * 256 + tid) * 4;
        const float4 v = *(const float4*)(Wl + i);
        us4 o;
        o.x = f2bf(v.x); o.y = f2bf(v.y); o.z = f2bf(v.z); o.w = f2bf(v.w);
        *(us4*)(Wlb + i) = o;
    } else if (b < 320) {
        const int bidx = b - 64;
        const int bx = bidx & 15, by = bidx >> 4;
#pragma unroll
        for (int p = 0; p < 16; ++p) {
            int idx = p * 256 + tid;
            int r = idx >> 6, c = idx & 63;
            t[r][c] = Wv[(long)(by * 64 + r) * 1024 + bx * 64 + c];
        }
        __syncthreads();
#pragma unroll
        for (int p = 0; p < 16; ++p) {
            int idx = p * 256 + tid;
            int c = idx >> 6, r = idx & 63;
            WvT[(long)(bx * 64 + c) * 1024 + by * 64 + r] = f2bf(t[r][c]);
        }
        if (bx == 0) rsc[by * 256 + tid] = 0.f;
    } else {
        const int row = (b - 320) * 4 + (tid >> 6);
        const int lane = tid & 63;
        float s = 0.f;
#pragma unroll
        for (int i = 0; i < 16; ++i) s += Wo[(long)row * 1024 + i * 64 + lane] * bv[i * 64 + lane];
        for (int o = 32; o; o >>= 1) s += __shfl_xor(s, o, 64);
        if (lane == 0) bocomb[row] = bo[row] + s;
    }
}

extern "C" void kernel_launch(void* const* d_in, const int* in_sizes, int n_in,
                              void* d_out, int out_size, void* d_ws, size_t ws_size,
                              hipStream_t stream)
{
    const float* query = (const float*)d_in[0];
    const float* key   = (const float*)d_in[1];
    const float* value = (const float*)d_in[2];
    const float* Wv    = (const float*)d_in[3];
    const float* bv    = (const float*)d_in[4];
    const float* Wl    = (const float*)d_in[5];
    const float* bl    = (const float*)d_in[6];
    const float* Wo    = (const float*)d_in[7];
    const float* bo    = (const float*)d_in[8];
    float* out = (float*)d_out;

    // B=2, L=2048, E=1024, M_land=64.
    // out = diag(1/rowsum(P)) P value Wov^T + 1*(Wo bv + bo)^T,
    //   P = exp(ql kl^T / 8),  Wov = Wo @ Wv,  Ut = Wov @ value^T.
    // q,k,value,Wo consumed as f32 directly (cast fused into GEMM staging).
    // DAG: prep -> {lmsm, wov}(fused23) -> {ut, p}(fused45) -> out(gemm6_sk).
    char* ws = (char*)d_ws;
    u16*   Wlb    = (u16*)  (ws + 25165824);   // [64,1024]
    u16*   WvT    = (u16*)  (ws + 27394048);   // [1024(e),1024(d)]
    u16*   Wov    = (u16*)  (ws + 29491200);   // [1024(o),1024(e)]
    u16*   qlkl   = (u16*)  (ws + 31588352);   // [8192,64] (ql then kl)
    u16*   Ut     = (u16*)  (ws + 32636928);   // [2,1024(o),2048(k)]
    u16*   Pm     = (u16*)  (ws + 41025536);   // [2,2048,2048]
    float* rsc    = (float*)(ws + 57802752);   // [2,2048] row sums of P
    float* bocomb = (float*)(ws + 57819136);   // [1024]

    // 1) prep (Wl cast + Wv transpose-cast + bias fold + rsc zero)
    prep_all<<<dim3(576), 256, 0, stream>>>(Wl, Wv, Wo, bv, bo,
                                            Wlb, WvT, rsc, bocomb);

    // 2+3) ql/kl landmark softmax  ||  Wov = Wo @ Wv   (one launch, 512 blocks)
    fused23<<<dim3(512), 256, 16384, stream>>>(query, key, Wlb, qlkl, bl,
                                               Wo, WvT, Wov);

    // 4+5) Ut[z] = Wov @ value[z]^T  ||  P[z] = exp(ql kl^T/8) + rowsums
    fused45<<<dim3(1024), 256, 32768, stream>>>(Wov, value, Ut, qlkl, Pm, rsc);

    // 6) out[z] = diag(1/rsc) P[z] @ Ut[z]^T + bocomb -> f32, in-block split-K
    gemm6_sk<<<dim3(8, 32, 2), 512, 49152, stream>>>(Pm, Ut, out, bocomb, rsc);
}

// Round 4
// 164.663 us; speedup vs baseline: 1.2222x; 1.0383x over previous
//
#include <hip/hip_runtime.h>
#include <hip/hip_bf16.h>
#include <cstdint>

typedef unsigned short u16;
typedef __attribute__((ext_vector_type(8))) short short8;
typedef __attribute__((ext_vector_type(4))) float f32x4;
typedef __attribute__((ext_vector_type(4))) unsigned short us4;

__device__ __forceinline__ u16 f2bf(float f) {
    union { float f; unsigned int i; } v; v.f = f;
    unsigned int x = v.i;
    unsigned int r = x + 0x7fffu + ((x >> 16) & 1u);  // RNE
    return (u16)(r >> 16);
}

enum { EPI_F32 = 0, EPI_BF16 = 1, EPI_EXP_RS = 3, EPI_F32_DIV_CB = 4, EPI_LMSM = 5 };

// C[M,N] = A[M,K] * B[N,K]^T (both K-contiguous). BK=64, 256 threads (4 waves
// 2x2). DOUBLE-BUFFERED K-loop (T3-minimum): per K-step, tile t+1's staging is
// issued BEFORE tile t's compute, with ONE __syncthreads per step — the drain
// then only waits the residue of loads that had the whole MFMA phase to land.
// bf16 operands stage via async global_load_lds(16B) with XOR-8 swizzle applied
// on the GLOBAL address side (LDS lane mapping fixed: base + lane*16): chunk
// slot c_l of row r holds global chunk c_l^(r&7). Fragment reads invert the
// XOR -> bank-balanced ds_read_b128. f32 operands (AF32/BF32) reg-stage with
// T14 split: float4 loads issued pre-compute, RNE-convert + ds_write(16B) into
// the identical swizzled slot post-compute, so the waitcnt sits after MFMA.
// A2x: optional second A source; rows >= M/2 come from it (q/k concat case).
template <int BM, int BN, int EPI, bool AF32, bool BF32>
__device__ __forceinline__ void gemm_body(
    char* __restrict__ smem,
    const void* __restrict__ Ax, const void* __restrict__ A2x,
    const void* __restrict__ Bx, void* __restrict__ Cv,
    int M, int N, int K, long sA, long sB, long sC,
    const float* __restrict__ biasCol, float* __restrict__ rowScale, float expScale,
    int m0, int n0, int z)
{
    constexpr int BK = 64;
    constexpr int MFRAG = (BM + 31) / 32;   // per-wave 16-row frags (wave covers BM/2)
    constexpr int NFRAG = BN / 32;
    constexpr int AG = (BM + 31) / 32;      // 32-row staging groups
    constexpr int BG = BN / 32;
    constexpr int TBUF = (BM + BN) * BK;    // u16 elems per LDS buffer

    const int tid = threadIdx.x;
    const int lane = tid & 63;
    const int quad = lane >> 4;
    const int l15 = lane & 15;
    const int w = tid >> 6;
    const int wm = w >> 1, wn = w & 1;

    const int r8 = tid >> 3;                    // 0..31 staging row within group
    const int cl = tid & 7;                     // LDS chunk slot (16B units)
    const int cg = ((cl ^ (r8 & 7)) * 8);       // swizzled global chunk (elements)

    const u16* ap[AG];
    const float* apf[AG];
    if constexpr (AF32) {
        const float* base = (const float*)Ax;
        long mr = m0;
        if (A2x != nullptr && m0 >= (M >> 1)) { base = (const float*)A2x; mr = m0 - (M >> 1); }
        const float* Afb = base + (long)z * sA + (long)mr * K;
#pragma unroll
        for (int j = 0; j < AG; ++j) apf[j] = Afb + (long)(j * 32 + r8) * K + cg;
    } else {
        const u16* Ab = (const u16*)Ax + (long)z * sA + (long)m0 * K;
#pragma unroll
        for (int j = 0; j < AG; ++j) ap[j] = Ab + (long)(j * 32 + r8) * K + cg;
    }
    const u16* bp[BG];
    const float* bpf[BG];
    if constexpr (BF32) {
        const float* Bfb = (const float*)Bx + (long)z * sB + (long)n0 * K;
#pragma unroll
        for (int j = 0; j < BG; ++j) bpf[j] = Bfb + (long)(j * 32 + r8) * K + cg;
    } else {
        const u16* Bb = (const u16*)Bx + (long)z * sB + (long)n0 * K;
#pragma unroll
        for (int j = 0; j < BG; ++j) bp[j] = Bb + (long)(j * 32 + r8) * K + cg;
    }

    f32x4 acc[MFRAG][NFRAG] = {};
    const int sw = l15 & 7;  // row XOR key for fragment reads
    u16* const base16 = (u16*)smem;
    const int NT = K / BK;

    // ---- prologue: stage tile 0 into buffer 0 ----
    {
        u16* As = base16;
        u16* Bs = base16 + BM * BK;
        if constexpr (!AF32) {
#pragma unroll
            for (int j = 0; j < AG; ++j) {
                __builtin_amdgcn_global_load_lds(
                    (const __attribute__((address_space(1))) void*)(ap[j]),
                    (__attribute__((address_space(3))) void*)(&As[(j * 32 + r8) * BK + cl * 8]),
                    16, 0, 0);
                ap[j] += BK;
            }
        } else {
#pragma unroll
            for (int j = 0; j < AG; ++j) {
                const float4 u0 = *(const float4*)(apf[j]);
                const float4 u1 = *(const float4*)(apf[j] + 4);
                short8 o;
                o[0] = (short)f2bf(u0.x); o[1] = (short)f2bf(u0.y);
                o[2] = (short)f2bf(u0.z); o[3] = (short)f2bf(u0.w);
                o[4] = (short)f2bf(u1.x); o[5] = (short)f2bf(u1.y);
                o[6] = (short)f2bf(u1.z); o[7] = (short)f2bf(u1.w);
                *(short8*)&As[(j * 32 + r8) * BK + cl * 8] = o;
                apf[j] += BK;
            }
        }
        if constexpr (!BF32) {
#pragma unroll
            for (int j = 0; j < BG; ++j) {
                __builtin_amdgcn_global_load_lds(
                    (const __attribute__((address_space(1))) void*)(bp[j]),
                    (__attribute__((address_space(3))) void*)(&Bs[(j * 32 + r8) * BK + cl * 8]),
                    16, 0, 0);
                bp[j] += BK;
            }
        } else {
#pragma unroll
            for (int j = 0; j < BG; ++j) {
                const float4 u0 = *(const float4*)(bpf[j]);
                const float4 u1 = *(const float4*)(bpf[j] + 4);
                short8 o;
                o[0] = (short)f2bf(u0.x); o[1] = (short)f2bf(u0.y);
                o[2] = (short)f2bf(u0.z); o[3] = (short)f2bf(u0.w);
                o[4] = (short)f2bf(u1.x); o[5] = (short)f2bf(u1.y);
                o[6] = (short)f2bf(u1.z); o[7] = (short)f2bf(u1.w);
                *(short8*)&Bs[(j * 32 + r8) * BK + cl * 8] = o;
                bpf[j] += BK;
            }
        }
    }
    __syncthreads();

    // ---- pipelined main loop: one barrier per K-step ----
    for (int t = 0; t < NT; ++t) {
        u16* Asc = base16 + (t & 1) * TBUF;
        u16* Bsc = Asc + BM * BK;
        u16* Asn = base16 + ((t + 1) & 1) * TBUF;
        u16* Bsn = Asn + BM * BK;
        const bool pf = (t + 1 < NT);

        float4 ra[AG][2];
        float4 rb[BG][2];
        if (pf) {
            if constexpr (!AF32) {
#pragma unroll
                for (int j = 0; j < AG; ++j) {
                    __builtin_amdgcn_global_load_lds(
                        (const __attribute__((address_space(1))) void*)(ap[j]),
                        (__attribute__((address_space(3))) void*)(&Asn[(j * 32 + r8) * BK + cl * 8]),
                        16, 0, 0);
                    ap[j] += BK;
                }
            } else {
#pragma unroll
                for (int j = 0; j < AG; ++j) {
                    ra[j][0] = *(const float4*)(apf[j]);
                    ra[j][1] = *(const float4*)(apf[j] + 4);
                    apf[j] += BK;
                }
            }
            if constexpr (!BF32) {
#pragma unroll
                for (int j = 0; j < BG; ++j) {
                    __builtin_amdgcn_global_load_lds(
                        (const __attribute__((address_space(1))) void*)(bp[j]),
                        (__attribute__((address_space(3))) void*)(&Bsn[(j * 32 + r8) * BK + cl * 8]),
                        16, 0, 0);
                    bp[j] += BK;
                }
            } else {
#pragma unroll
                for (int j = 0; j < BG; ++j) {
                    rb[j][0] = *(const float4*)(bpf[j]);
                    rb[j][1] = *(const float4*)(bpf[j] + 4);
                    bpf[j] += BK;
                }
            }
        }

#pragma unroll
        for (int ks = 0; ks < 2; ++ks) {
            short8 af[MFRAG], bfr[NFRAG];
#pragma unroll
            for (int i = 0; i < MFRAG; ++i)
                af[i] = *(const short8*)&Asc[(wm * (BM / 2) + i * 16 + l15) * BK +
                                             (((ks * 4 + quad) ^ sw) * 8)];
#pragma unroll
            for (int i = 0; i < NFRAG; ++i)
                bfr[i] = *(const short8*)&Bsc[(wn * (BN / 2) + i * 16 + l15) * BK +
                                              (((ks * 4 + quad) ^ sw) * 8)];
#pragma unroll
            for (int i = 0; i < MFRAG; ++i)
#pragma unroll
                for (int jn = 0; jn < NFRAG; ++jn)
                    acc[i][jn] = __builtin_amdgcn_mfma_f32_16x16x32_bf16(af[i], bfr[jn], acc[i][jn], 0, 0, 0);
        }

        if (pf) {
            if constexpr (AF32) {
#pragma unroll
                for (int j = 0; j < AG; ++j) {
                    short8 o;
                    o[0] = (short)f2bf(ra[j][0].x); o[1] = (short)f2bf(ra[j][0].y);
                    o[2] = (short)f2bf(ra[j][0].z); o[3] = (short)f2bf(ra[j][0].w);
                    o[4] = (short)f2bf(ra[j][1].x); o[5] = (short)f2bf(ra[j][1].y);
                    o[6] = (short)f2bf(ra[j][1].z); o[7] = (short)f2bf(ra[j][1].w);
                    *(short8*)&Asn[(j * 32 + r8) * BK + cl * 8] = o;
                }
            }
            if constexpr (BF32) {
#pragma unroll
                for (int j = 0; j < BG; ++j) {
                    short8 o;
                    o[0] = (short)f2bf(rb[j][0].x); o[1] = (short)f2bf(rb[j][0].y);
                    o[2] = (short)f2bf(rb[j][0].z); o[3] = (short)f2bf(rb[j][0].w);
                    o[4] = (short)f2bf(rb[j][1].x); o[5] = (short)f2bf(rb[j][1].y);
                    o[6] = (short)f2bf(rb[j][1].z); o[7] = (short)f2bf(rb[j][1].w);
                    *(short8*)&Bsn[(j * 32 + r8) * BK + cl * 8] = o;
                }
            }
        }
        __syncthreads();
    }

    // C/D layout: col=lane&15, row=quad*4+reg (m89/m91 verified).
    if constexpr (EPI == EPI_LMSM) {
        // BM=32, BN=64, single n-block: full softmax row inside the block.
        float* red = (float*)(base16 + 2 * TBUF);  // [2][BM]
        float ev[4][NFRAG];
#pragma unroll
        for (int r = 0; r < 4; ++r) {
            float s = 0.f;
#pragma unroll
            for (int jn = 0; jn < NFRAG; ++jn) {
                const int col = wn * (BN / 2) + jn * 16 + l15;
                float v = exp2f((acc[0][jn][r] + biasCol[col]) * expScale);
                ev[r][jn] = v; s += v;
            }
            s += __shfl_xor(s, 1); s += __shfl_xor(s, 2);
            s += __shfl_xor(s, 4); s += __shfl_xor(s, 8);
            if (l15 == 0) red[wn * BM + wm * 16 + quad * 4 + r] = s;
        }
        __syncthreads();
#pragma unroll
        for (int r = 0; r < 4; ++r) {
            const int mrow = wm * 16 + quad * 4 + r;
            const float inv = 1.0f / (red[mrow] + red[BM + mrow]);
            const long m = m0 + mrow;
#pragma unroll
            for (int jn = 0; jn < NFRAG; ++jn) {
                const int col = wn * (BN / 2) + jn * 16 + l15;
                ((u16*)Cv)[m * N + col] = f2bf(ev[r][jn] * inv);
            }
        }
        return;
    } else {
#pragma unroll
        for (int i = 0; i < MFRAG; ++i) {
            const int mb = m0 + wm * (BM / 2) + i * 16 + quad * 4;
#pragma unroll
            for (int r = 0; r < 4; ++r) {
                const int m = mb + r;
                float rin = 0.f;
                if constexpr (EPI == EPI_F32_DIV_CB) rin = 1.0f / rowScale[(long)z * M + m];
                float rowsum = 0.f;
#pragma unroll
                for (int jn = 0; jn < NFRAG; ++jn) {
                    const int col = n0 + wn * (BN / 2) + jn * 16 + l15;
                    float v = acc[i][jn][r];
                    if constexpr (EPI == EPI_EXP_RS) { v = exp2f(v * expScale); rowsum += v; }
                    if constexpr (EPI == EPI_F32_DIV_CB) v = v * rin + biasCol[col];
                    if constexpr (EPI == EPI_F32 || EPI == EPI_F32_DIV_CB)
                        ((float*)Cv)[(long)z * sC + (long)m * N + col] = v;
                    else
                        ((u16*)Cv)[(long)z * sC + (long)m * N + col] = f2bf(v);
                }
                if constexpr (EPI == EPI_EXP_RS) {
                    rowsum += __shfl_xor(rowsum, 1);
                    rowsum += __shfl_xor(rowsum, 2);
                    rowsum += __shfl_xor(rowsum, 4);
                    rowsum += __shfl_xor(rowsum, 8);
                    if (l15 == 0) atomicAdd(&rowScale[(long)z * M + m], rowsum);
                }
            }
        }
    }
}

// Thin grid wrapper for standalone GEMM launches (gemm6).
template <int BM, int BN, int EPI, bool AF32, bool BF32>
__global__ void __launch_bounds__(256)
gemm_bt(const void* __restrict__ Ax, const void* __restrict__ A2x,
        const void* __restrict__ Bx, void* __restrict__ Cv,
        int M, int N, int K, long sA, long sB, long sC,
        const float* __restrict__ biasCol, float* __restrict__ rowScale, float expScale)
{
    extern __shared__ char smem[];
    gemm_body<BM, BN, EPI, AF32, BF32>(smem, Ax, A2x, Bx, Cv, M, N, K, sA, sB, sC,
                                       biasCol, rowScale, expScale,
                                       blockIdx.y * BM, blockIdx.x * BN, blockIdx.z);
}

// Fused launch A: blocks [0,256) = ql/kl landmark softmax (LMSM, q/k read f32);
//                 blocks [256,512) = Wov = Wo(f32) @ WvT  (independent GEMMs,
// merged at grid level: 2 blocks/CU instead of two serialized 1-block/CU runs).
__global__ void __launch_bounds__(256)
fused23(const float* __restrict__ query, const float* __restrict__ key,
        const u16* __restrict__ Wlb, u16* __restrict__ qlkl,
        const float* __restrict__ bl,
        const float* __restrict__ Wo, const u16* __restrict__ WvT, u16* __restrict__ Wov)
{
    extern __shared__ char smem[];
    const int b = blockIdx.x;
    if (b < 256) {
        gemm_body<32, 64, EPI_LMSM, true, false>(smem, query, key, Wlb, qlkl,
            8192, 64, 1024, 0, 0, 0, bl, nullptr, 0.18033688011112042f,
            b * 32, 0, 0);
    } else {
        const int t = b - 256;
        gemm_body<64, 64, EPI_BF16, true, false>(smem, Wo, nullptr, WvT, Wov,
            1024, 1024, 1024, 0, 0, 0, nullptr, nullptr, 0.f,
            (t >> 4) * 64, (t & 15) * 64, 0);
    }
}

// Fused launch B: blocks [0,512)    = Ut[z] = Wov @ value[z]^T (value read f32);
//                 blocks [512,1024) = P[z] = exp(ql kl^T / 8) + row-sum atomics.
__global__ void __launch_bounds__(256)
fused45(const u16* __restrict__ Wov, const float* __restrict__ value, u16* __restrict__ Ut,
        const u16* __restrict__ qlkl, u16* __restrict__ Pm, float* __restrict__ rsc)
{
    extern __shared__ char smem[];
    const int b = blockIdx.x;
    if (b < 512) {
        const int x = b & 31, y = (b >> 5) & 7, z = b >> 8;
        gemm_body<128, 64, EPI_BF16, false, true>(smem, Wov, nullptr, value, Ut,
            1024, 2048, 1024, 0, 2097152, 2097152, nullptr, nullptr, 0.f,
            y * 128, x * 64, z);
    } else {
        const int t = b - 512;
        const int x = t & 15, y = (t >> 4) & 15, z = t >> 8;
        gemm_body<128, 128, EPI_EXP_RS, false, false>(smem, qlkl, nullptr, qlkl + 262144, Pm,
            2048, 2048, 64, 131072, 131072, 4194304, nullptr, rsc, 0.18033688011112042f,
            y * 128, x * 128, z);
    }
}

// Prep in ONE launch, block-range dispatched:
//   blocks [0,64):    cast Wl (64K elems) f32->bf16
//   blocks [64,320):  WvT[e,d] = bf16(Wv[d,e]) via padded LDS tile; zero rsc
//   blocks [320,576): bocomb = bo + Wo @ bv (one wave per row)
__global__ void __launch_bounds__(256)
prep_all(const float* __restrict__ Wl, const float* __restrict__ Wv,
         const float* __restrict__ Wo, const float* __restrict__ bv,
         const float* __restrict__ bo,
         u16* __restrict__ Wlb, u16* __restrict__ WvT,
         float* __restrict__ rsc, float* __restrict__ bocomb)
{
    __shared__ float t[64][65];
    const int b = blockIdx.x;
    const int tid = threadIdx.x;
    if (b < 64) {
        long i = ((long)b * 256 + tid) * 4;
        const float4 v = *(const float4*)(Wl + i);
        us4 o;
        o.x = f2bf(v.x); o.y = f2bf(v.y); o.z = f2bf(v.z); o.w = f2bf(v.w);
        *(us4*)(Wlb + i) = o;
    } else if (b < 320) {
        const int bidx = b - 64;
        const int bx = bidx & 15, by = bidx >> 4;
#pragma unroll
        for (int p = 0; p < 16; ++p) {
            int idx = p * 256 + tid;
            int r = idx >> 6, c = idx & 63;
            t[r][c] = Wv[(long)(by * 64 + r) * 1024 + bx * 64 + c];
        }
        __syncthreads();
#pragma unroll
        for (int p = 0; p < 16; ++p) {
            int idx = p * 256 + tid;
            int c = idx >> 6, r = idx & 63;
            WvT[(long)(bx * 64 + c) * 1024 + by * 64 + r] = f2bf(t[r][c]);
        }
        if (bx == 0) rsc[by * 256 + tid] = 0.f;
    } else {
        const int row = (b - 320) * 4 + (tid >> 6);
        const int lane = tid & 63;
        float s = 0.f;
#pragma unroll
        for (int i = 0; i < 16; ++i) s += Wo[(long)row * 1024 + i * 64 + lane] * bv[i * 64 + lane];
        for (int o = 32; o; o >>= 1) s += __shfl_xor(s, o, 64);
        if (lane == 0) bocomb[row] = bo[row] + s;
    }
}

extern "C" void kernel_launch(void* const* d_in, const int* in_sizes, int n_in,
                              void* d_out, int out_size, void* d_ws, size_t ws_size,
                              hipStream_t stream)
{
    const float* query = (const float*)d_in[0];
    const float* key   = (const float*)d_in[1];
    const float* value = (const float*)d_in[2];
    const float* Wv    = (const float*)d_in[3];
    const float* bv    = (const float*)d_in[4];
    const float* Wl    = (const float*)d_in[5];
    const float* bl    = (const float*)d_in[6];
    const float* Wo    = (const float*)d_in[7];
    const float* bo    = (const float*)d_in[8];
    float* out = (float*)d_out;

    // B=2, L=2048, E=1024, M_land=64.
    // out = diag(1/rowsum(P)) P value Wov^T + 1*(Wo bv + bo)^T,
    //   P = exp(ql kl^T / 8),  Wov = Wo @ Wv,  Ut = Wov @ value^T.
    // q,k,value,Wo consumed as f32 directly (cast fused into GEMM staging).
    // DAG: prep -> {lmsm, wov}(fused23) -> {ut, p}(fused45) -> out(gemm6).
    char* ws = (char*)d_ws;
    u16*   Wlb    = (u16*)  (ws + 25165824);   // [64,1024]
    u16*   WvT    = (u16*)  (ws + 27394048);   // [1024(e),1024(d)]
    u16*   Wov    = (u16*)  (ws + 29491200);   // [1024(o),1024(e)]
    u16*   qlkl   = (u16*)  (ws + 31588352);   // [8192,64] (ql then kl)
    u16*   Ut     = (u16*)  (ws + 32636928);   // [2,1024(o),2048(k)]
    u16*   Pm     = (u16*)  (ws + 41025536);   // [2,2048,2048]
    float* rsc    = (float*)(ws + 57802752);   // [2,2048] row sums of P
    float* bocomb = (float*)(ws + 57819136);   // [1024]

    // 1) prep (Wl cast + Wv transpose-cast + bias fold + rsc zero)
    prep_all<<<dim3(576), 256, 0, stream>>>(Wl, Wv, Wo, bv, bo,
                                            Wlb, WvT, rsc, bocomb);

    // 2+3) ql/kl landmark softmax  ||  Wov = Wo @ Wv   (one launch, 512 blocks)
    // smem: Wov dbuf 2*(64+64)*64*2 = 32768; LMSM needs 24832 <= that.
    fused23<<<dim3(512), 256, 32768, stream>>>(query, key, Wlb, qlkl, bl,
                                               Wo, WvT, Wov);

    // 4+5) Ut[z] = Wov @ value[z]^T  ||  P[z] = exp(ql kl^T/8) + rowsums
    // smem: Ut dbuf 2*(128+64)*64*2 = 49152; P (K=64, single tile) uses 32768.
    fused45<<<dim3(1024), 256, 49152, stream>>>(Wov, value, Ut, qlkl, Pm, rsc);

    // 6) out[z] = diag(1/rsc) P[z] @ Ut[z]^T + bocomb -> f32 (dbuf 49152)
    gemm_bt<64, 128, EPI_F32_DIV_CB, false, false>
        <<<dim3(8, 32, 2), 256, 49152, stream>>>(
        Pm, nullptr, Ut, out, 2048, 1024, 2048,
        4194304, 2097152, 2097152, bocomb, rsc, 0.f);
}